// Round 1
// 189.184 us; speedup vs baseline: 1.0896x; 1.0896x over previous
//
#include <hip/hip_runtime.h>
#include <stdint.h>

#define B_    32768
#define C_    64
#define D_    8
#define K15_  15
#define K16_  16
#define OUT_  512

typedef _Float16 half4v __attribute__((ext_vector_type(4)));
typedef _Float16 half8  __attribute__((ext_vector_type(8)));

// workspace layout (bytes)
#define AMAP_OFF  0
#define AMAP_SZ   32768                  // uint8 argmax per 15-bit code
#define S64_OFF   32768                  // fp64 S, k-major: S64[c][k][d]
#define S64_SZ    (64 * 15 * 8 * 8)      // 61440
#define T64_OFF   (S64_OFF + S64_SZ)     // 94208
#define T64_SZ    (64 * 15 * 8)          // 7680
#define IDX_OFF   (T64_OFF + T64_SZ)     // 101888
#define IDX_SZ    (B_ * C_)              // 2 MB
#define PCT_OFF   (IDX_OFF + IDX_SZ)     // 2199040
#define PCT_SZ    (B_ * 32)              // 1 MB: pcT[p][rg][tr][i]
#define PTAB_OFF  (PCT_OFF + PCT_SZ)     // 3247616 (16B aligned)
#define PTAB_SZ   (32 * 32 * 256 * 16 * 2) // 8388608: P5[p][jc][q][16] fp16
#define WS_NEED   ((size_t)PTAB_OFF + PTAB_SZ)

// ---------------------------------------------------------------------------
// k_setup (fused): 2048 blocks write P5 (j-first layout, fully coalesced
// 16B stores); blocks 0..127 also compute amap; block 128 builds S64/T64.
// P5 half-index: ((p*32 + jc)*256 + q)*16 + e   (q = (t0<<4)|t1)
// ---------------------------------------------------------------------------
__global__ __launch_bounds__(256) void k_setup(const float* __restrict__ LUT,
                                               const float* __restrict__ H,
                                               const float* __restrict__ S,
                                               const float* __restrict__ T,
                                               _Float16* __restrict__ P5,
                                               uint8_t* __restrict__ amap,
                                               double* __restrict__ S64,
                                               double* __restrict__ T64,
                                               int do_pairs) {
    int gid = blockIdx.x * 256 + threadIdx.x;

    if (do_pairs) {
        // gid bits: [p:5][jc:5][q:8][e8:1] -> write offset = gid*8 halfs
        int e8 = gid & 1;
        int q = (gid >> 1) & 255;
        int jc = (gid >> 9) & 31;
        int p = gid >> 14;
        int t0 = q >> 4;
        int t1 = q & 15;
        int j0 = jc * 16 + e8 * 8;
        const float* u = LUT + (size_t)((2 * p) * 16 + t0) * 512 + j0;
        const float* v = LUT + (size_t)((2 * p + 1) * 16 + t1) * 512 + j0;
        float4 u0 = ((const float4*)u)[0];
        float4 u1 = ((const float4*)u)[1];
        float4 v0 = ((const float4*)v)[0];
        float4 v1 = ((const float4*)v)[1];
        half8 w;
        w[0] = (_Float16)(u0.x + v0.x);
        w[1] = (_Float16)(u0.y + v0.y);
        w[2] = (_Float16)(u0.z + v0.z);
        w[3] = (_Float16)(u0.w + v0.w);
        w[4] = (_Float16)(u1.x + v1.x);
        w[5] = (_Float16)(u1.y + v1.y);
        w[6] = (_Float16)(u1.z + v1.z);
        w[7] = (_Float16)(u1.w + v1.w);
        *(half8*)(P5 + (size_t)gid * 8) = w;
    }

    if (blockIdx.x < 128) {
        int code = gid;
        double h[K16_];
#pragma unroll
        for (int j = 0; j < K16_; ++j) h[j] = 0.0;
#pragma unroll
        for (int k = 0; k < K15_; ++k) {
            double s = ((code >> k) & 1) ? 1.0 : -1.0;
#pragma unroll
            for (int j = 0; j < K16_; ++j) h[j] += s * (double)H[k * K16_ + j];
        }
        double best = h[0];
        int bi = 0;
#pragma unroll
        for (int j = 1; j < K16_; ++j) {
            if (h[j] > best) { best = h[j]; bi = j; }
        }
        amap[code] = (uint8_t)bi;
    } else if (blockIdx.x == 128) {
        for (int i = threadIdx.x; i < 64 * 15 * 8; i += 256) {
            int c = i / 120;
            int r = i - c * 120;  // r = k*8 + d
            int k = r >> 3;
            int d = r & 7;
            S64[i] = (double)S[c * 120 + d * 15 + k];
        }
        for (int i = threadIdx.x; i < 64 * 15; i += 256) T64[i] = (double)T[i];
    }
}

// ---------------------------------------------------------------------------
// k_codes2: block = 256 thr (4 waves), 64 batches per block.
// Stage x into LDS transposed, wave<->channel, lane<->batch: S/T wave-uniform
// scalar loads; fp64 dot products. Writes idx bytes + transposed pair codes
// pcT[p][rg=row>>10][tr=row&127][i=(row&1023)>>7].
// ---------------------------------------------------------------------------
#define XSTRIDE 585   // odd -> conflict-free
__global__ __launch_bounds__(256) void k_codes2(const float* __restrict__ x,
                                                const double* __restrict__ S64,
                                                const double* __restrict__ T64,
                                                const uint8_t* __restrict__ amap,
                                                uint8_t* __restrict__ idxo,
                                                uint8_t* __restrict__ pcT) {
    __shared__ float xls[32 * XSTRIDE];
    __shared__ uint8_t idsh[64 * 68];

    int b0 = blockIdx.x * 64;
    int lane = threadIdx.x & 63;
    int wv = __builtin_amdgcn_readfirstlane(threadIdx.x >> 6);

    for (int half = 0; half < 2; ++half) {
        __syncthreads();
#pragma unroll
        for (int t = 0; t < 16; ++t) {
            int e = t * 256 + threadIdx.x;
            int b = e >> 6;
            int j4 = e & 63;
            float4 v = ((const float4*)(x + (size_t)(b0 + b) * 512 +
                                        half * 256))[j4];
            int cl = j4 >> 1;
            int d0 = (j4 & 1) * 4;
            float* dst = &xls[cl * XSTRIDE + b * 9 + d0];
            dst[0] = v.x; dst[1] = v.y; dst[2] = v.z; dst[3] = v.w;
        }
        __syncthreads();
        for (int i = 0; i < 8; ++i) {
            int cl = wv + i * 4;                 // wave-uniform
            int c = half * 32 + cl;
            const double* Sc = S64 + c * 120;    // k-major: Sc[k*8+d]
            const double* Tc = T64 + c * 15;
            double xd[8];
#pragma unroll
            for (int d = 0; d < 8; ++d)
                xd[d] = (double)xls[cl * XSTRIDE + lane * 9 + d];
            unsigned code = 0;
#pragma unroll
            for (int k = 0; k < K15_; ++k) {
                double p = -Tc[k];
#pragma unroll
                for (int d = 0; d < 8; ++d) p = fma(xd[d], Sc[k * 8 + d], p);
                code |= (p > 0.0) ? (1u << k) : 0u;
            }
            idsh[lane * 68 + c] = amap[code];
        }
    }
    __syncthreads();

    int bb = threadIdx.x >> 2;
    int q = threadIdx.x & 3;
    {
        uint32_t w0 = *(const uint32_t*)&idsh[bb * 68 + q * 16 + 0];
        uint32_t w1 = *(const uint32_t*)&idsh[bb * 68 + q * 16 + 4];
        uint32_t w2 = *(const uint32_t*)&idsh[bb * 68 + q * 16 + 8];
        uint32_t w3 = *(const uint32_t*)&idsh[bb * 68 + q * 16 + 12];
        uint32_t* o = (uint32_t*)(idxo + (size_t)(b0 + bb) * 64 + q * 16);
        o[0] = w0; o[1] = w1; o[2] = w2; o[3] = w3;
    }
    {
        int row = b0 + bb;
        int rg = row >> 10;
        int tr = row & 127;
        int i_ = (row & 1023) >> 7;
        uint8_t* base = pcT + rg * 1024 + tr * 8 + i_;
#pragma unroll
        for (int pi = 0; pi < 8; ++pi) {
            int p = q * 8 + pi;
            uint8_t byte = (uint8_t)((idsh[bb * 68 + 2 * p] << 4) |
                                     idsh[bb * 68 + 2 * p + 1]);
            base[p * 32768] = byte;
        }
    }
}

// ---------------------------------------------------------------------------
// k_main6: streaming-staged gather, v2.
// Block (rg = blk>>5, jc = blk&31) owns 1024 rows x 16 output halfs.
// Changes vs k_main5:
//   * slab row stride 24 halfs (48 B): 16B-aligned -> ONE ds_read_b128 per
//     row gather (was 2x ds_read_b64 at 40 B stride). Quad-bank index
//     (3*ci + tc) & 7 is uniform for random ci -> near the 8-clock wave64
//     b128 floor instead of ~2x random-conflict serialization.
//   * stage writes are 2x aligned ds_write_b128, quad walk (3t+w)&7 ->
//     conflict-free.
//   * double-buffered slab (2 x 12 KB): ONE barrier per pair (was 2).
//     Safety: write(p)->bar(p)->gather(p); gather(p) vs write(p+2) on the
//     same buffer are separated by bar(p+1).
//   * slab+codes prefetch for p+1 issued before the barrier -> L2 latency
//     hides under the gather of p.
// LDS 24576 B/block -> 4 blocks/CU (98 KB), launch_bounds(256,4) caps VGPR.
// jc = blk&31 pins all 32 rg-readers of a slab to one XCD's L2 (unchanged).
// ---------------------------------------------------------------------------
__global__ __launch_bounds__(256, 4) void k_main6(const uint8_t* __restrict__ pcT,
                                                  const _Float16* __restrict__ P5,
                                                  float* __restrict__ out) {
    __shared__ alignas(16) _Float16 slab[2][256 * 24];  // 48 B per code row

    int rg = blockIdx.x >> 5;
    int jc = blockIdx.x & 31;
    int t = threadIdx.x;
    int tc = t & 1;        // which 8-half piece of the 16-half chunk
    int tr = t >> 1;       // 0..127, rows tr + 128*i

    const _Float16* src0 = P5 + ((size_t)(0 * 32 + jc) * 256 + t) * 16;
    const uint8_t* cbase = pcT + rg * 1024 + tr * 8;

    float acc[8][8];
#pragma unroll
    for (int i = 0; i < 8; ++i)
#pragma unroll
        for (int e = 0; e < 8; ++e) acc[i][e] = 0.f;

    // prefetch p=0
    half8 g0 = ((const half8*)src0)[0];
    half8 g1 = ((const half8*)src0)[1];
    uint64_t cw = *(const uint64_t*)cbase;

    for (int p = 0; p < 32; ++p) {
        // stage slab for p into buffer p&1 (aligned b128 writes, no conflict)
        _Float16* wb = &slab[p & 1][0];
        *(half8*)(wb + t * 24) = g0;
        *(half8*)(wb + t * 24 + 8) = g1;

        uint64_t cw_cur = cw;
        if (p < 31) {  // issue prefetch of p+1 BEFORE the barrier
            const _Float16* srcn =
                P5 + ((size_t)((p + 1) * 32 + jc) * 256 + t) * 16;
            g0 = ((const half8*)srcn)[0];
            g1 = ((const half8*)srcn)[1];
            cw = *(const uint64_t*)(cbase + (size_t)(p + 1) * 32768);
        }

        __syncthreads();  // slab p ready; also fences gather(p-1) vs write(p+1)

        const _Float16* rb = &slab[p & 1][0] + tc * 8;
#pragma unroll
        for (int i = 0; i < 8; ++i) {
            int ci = (int)((cw_cur >> (8 * i)) & 0xFF);
            half8 v = *(const half8*)(rb + ci * 24);  // one ds_read_b128
#pragma unroll
            for (int e = 0; e < 8; ++e) acc[i][e] += (float)v[e];
        }
    }

#pragma unroll
    for (int i = 0; i < 8; ++i) {
        int row = rg * 1024 + i * 128 + tr;
        float* o = out + (size_t)row * 512 + jc * 16 + tc * 8;
        float4 w0;
        w0.x = acc[i][0]; w0.y = acc[i][1]; w0.z = acc[i][2]; w0.w = acc[i][3];
        float4 w1;
        w1.x = acc[i][4]; w1.y = acc[i][5]; w1.z = acc[i][6]; w1.w = acc[i][7];
        ((float4*)o)[0] = w0;
        ((float4*)o)[1] = w1;
    }
}

// Fallback (small ws): direct 64-channel gather from fp32 LUT.
__global__ __launch_bounds__(256) void k_main_direct(const uint8_t* __restrict__ idx,
                                                     const float* __restrict__ LUT,
                                                     float* __restrict__ out) {
    int j4 = threadIdx.x & 127;
    int sub = threadIdx.x >> 7;
    int b0 = blockIdx.x * 16 + sub * 8;
    const float4* L4 = (const float4*)LUT;
    for (int r = 0; r < 8; ++r) {
        int b = b0 + r;
        const uint32_t* iw = (const uint32_t*)(idx + (size_t)b * 64);
        float4 acc;
        acc.x = 0.f; acc.y = 0.f; acc.z = 0.f; acc.w = 0.f;
#pragma unroll
        for (int i = 0; i < 16; ++i) {
            uint32_t w = __builtin_amdgcn_readfirstlane(iw[i]);
#pragma unroll
            for (int t = 0; t < 4; ++t) {
                int c = i * 4 + t;
                uint32_t codev = (w >> (8 * t)) & 0xFu;
                float4 v = L4[(size_t)(c * 16 + codev) * 128 + j4];
                acc.x += v.x; acc.y += v.y; acc.z += v.z; acc.w += v.w;
            }
        }
        ((float4*)(out + (size_t)b * 512))[j4] = acc;
    }
}

extern "C" void kernel_launch(void* const* d_in, const int* in_sizes, int n_in,
                              void* d_out, int out_size, void* d_ws, size_t ws_size,
                              hipStream_t stream) {
    const float* x   = (const float*)d_in[0];
    const float* S   = (const float*)d_in[1];
    const float* H   = (const float*)d_in[2];
    const float* T   = (const float*)d_in[3];
    const float* LUT = (const float*)d_in[4];
    float* out = (float*)d_out;

    uint8_t* ws = (uint8_t*)d_ws;
    uint8_t* amap = ws + AMAP_OFF;
    double* S64   = (double*)(ws + S64_OFF);
    double* T64   = (double*)(ws + T64_OFF);
    uint8_t* idxb = ws + IDX_OFF;
    uint8_t* pcTb = ws + PCT_OFF;
    _Float16* P5  = (_Float16*)(ws + PTAB_OFF);

    bool use_pairs = ws_size >= WS_NEED;

    hipLaunchKernelGGL(k_setup, dim3(use_pairs ? 2048 : 129), dim3(256), 0,
                       stream, LUT, H, S, T, P5, amap, S64, T64,
                       use_pairs ? 1 : 0);
    hipLaunchKernelGGL(k_codes2, dim3(B_ / 64), dim3(256), 0, stream,
                       x, S64, T64, amap, idxb, pcTb);
    if (use_pairs) {
        hipLaunchKernelGGL(k_main6, dim3(1024), dim3(256), 0, stream,
                           pcTb, P5, out);
    } else {
        hipLaunchKernelGGL(k_main_direct, dim3(B_ / 16), dim3(256), 0, stream,
                           idxb, LUT, out);
    }
}